// Round 2
// baseline (166.557 us; speedup 1.0000x reference)
//
#include <hip/hip_runtime.h>

#define B_ 64
#define T_ 2048
#define H_ 512
#define A_ 512

typedef unsigned short u16;
typedef __attribute__((ext_vector_type(8))) short bf16x8;
typedef __attribute__((ext_vector_type(4))) float f32x4;

__device__ __forceinline__ u16 f2bf(float f) {
  unsigned u = __float_as_uint(f);
  unsigned r = (u + 0x7FFFu + ((u >> 16) & 1u)) >> 16;  // RNE
  return (u16)r;
}

__device__ __forceinline__ float fast_tanh(float x) {
  float e = __expf(2.0f * x);
  return 1.0f - 2.0f * __builtin_amdgcn_rcpf(e + 1.0f);
}

// ---------------- K1: merged W_enc conversion + dec_proj -------------------
// blocks [0,128): W_enc fp32 -> bf16 fragment-tiled
//   unit idx = ks*2048 + (a>>4)*64 + q*16 + (a&15), holds W_enc[a][ks*32+q*8..+8]
// blocks [128,640): dec_proj[b][a] = dot(dec[b,:], W_dec[a,:])
__global__ void k_prep(const float* __restrict__ W, u16* __restrict__ wsB,
                       const float* __restrict__ dec, const float* __restrict__ Wd,
                       float* __restrict__ dp) {
  __shared__ float dl[H_];
  int tid = threadIdx.x;
  int bx = blockIdx.x;
  if (bx < 128) {
    int u = bx * 256 + tid;  // 32768 units
    int a = u >> 6;
    int hq = u & 63;
    int ks = hq >> 2;
    int q = hq & 3;
    const float4* src = (const float4*)(W + a * H_ + hq * 8);
    float4 x0 = src[0], x1 = src[1];
    uint4 pk;
    pk.x = (unsigned)f2bf(x0.x) | ((unsigned)f2bf(x0.y) << 16);
    pk.y = (unsigned)f2bf(x0.z) | ((unsigned)f2bf(x0.w) << 16);
    pk.z = (unsigned)f2bf(x1.x) | ((unsigned)f2bf(x1.y) << 16);
    pk.w = (unsigned)f2bf(x1.z) | ((unsigned)f2bf(x1.w) << 16);
    int dst = ks * 2048 + (a >> 4) * 64 + q * 16 + (a & 15);
    ((uint4*)wsB)[dst] = pk;
  } else {
    int e = bx - 128;        // 512 blocks
    int b = e >> 3;
    int a0 = (e & 7) * 64;
    dl[tid] = dec[b * H_ + tid];
    dl[tid + 256] = dec[b * H_ + tid + 256];
    __syncthreads();
    int al = tid >> 2, p = tid & 3;
    const float4* wr = (const float4*)(Wd + (a0 + al) * H_ + p * 128);
    const float4* dv = (const float4*)(dl + p * 128);
    float s = 0.f;
#pragma unroll 8
    for (int i = 0; i < 32; ++i) {
      float4 w4 = wr[i], d4 = dv[i];
      s += w4.x * d4.x + w4.y * d4.y + w4.z * d4.z + w4.w * d4.w;
    }
    s += __shfl_xor(s, 1);
    s += __shfl_xor(s, 2);
    if (p == 0) dp[b * H_ + a0 + al] = s;
  }
}

// ---------------- K2: fused enc_proj GEMM + tanh + V-dot -> scores ---------
// block: 64 rows x A=512. 8 waves, wave w owns cols [w*64, w*64+64).
// Double-buffered LDS, stage-before-compute, ONE barrier per K-step.
__launch_bounds__(512, 4)
__global__ void k_scores(const float* __restrict__ enc, const u16* __restrict__ wsB,
                         const float* __restrict__ dpj, const float* __restrict__ V,
                         float* __restrict__ scores) {
  __shared__ u16 Ab[2][64 * 32];    // 2 x 4 KB, fragment-tiled
  __shared__ u16 Bb[2][512 * 32];   // 2 x 32 KB, fragment-tiled
  __shared__ float red[8][64];
  int tid = threadIdx.x;
  int w = tid >> 6, l = tid & 63;
  int q = l >> 4, r = l & 15;
  int m0 = blockIdx.x * 64;
  int b = m0 >> 11;

  f32x4 acc[4][4];
#pragma unroll
  for (int m = 0; m < 4; ++m)
#pragma unroll
    for (int n = 0; n < 4; ++n) acc[m][n] = (f32x4){0.f, 0.f, 0.f, 0.f};

  // A-staging decode: thread t writes 8B = half of unit ut
  int ut = tid >> 1, h = tid & 1;
  int smf = ut >> 6, sq = (ut >> 4) & 3, sr = ut & 15;
  const float* abase = enc + (size_t)(m0 + smf * 16 + sr) * H_ + sq * 8 + h * 4;

  // prologue: stage ks=0 into buffer 0
  {
#pragma unroll
    for (int i = 0; i < 4; ++i) {
      int ubase = w * 256 + i * 64;
      __builtin_amdgcn_global_load_lds(
          (const __attribute__((address_space(1))) unsigned int*)(wsB + (size_t)(ubase + l) * 8),
          (__attribute__((address_space(3))) unsigned int*)(&Bb[0][ubase * 8]),
          16, 0, 0);
    }
    float4 x = *((const float4*)abase);
    uint2 pk;
    pk.x = (unsigned)f2bf(x.x) | ((unsigned)f2bf(x.y) << 16);
    pk.y = (unsigned)f2bf(x.z) | ((unsigned)f2bf(x.w) << 16);
    *((uint2*)&Ab[0][ut * 8 + h * 4]) = pk;
  }
  __syncthreads();

  for (int ks = 0; ks < 16; ++ks) {
    int cur = ks & 1, nxt = cur ^ 1;
    float4 xn;
    if (ks < 15) {
      // issue next A loads early (reg-staged; consumed after MFMA)
      xn = *((const float4*)(abase + (ks + 1) * 32));
      // issue next B global->LDS (drained by the end-of-iter barrier)
      const u16* bsrc = wsB + (size_t)(ks + 1) * (512 * 32);
#pragma unroll
      for (int i = 0; i < 4; ++i) {
        int ubase = w * 256 + i * 64;
        __builtin_amdgcn_global_load_lds(
            (const __attribute__((address_space(1))) unsigned int*)(bsrc + (size_t)(ubase + l) * 8),
            (__attribute__((address_space(3))) unsigned int*)(&Bb[nxt][ubase * 8]),
            16, 0, 0);
      }
    }

    bf16x8 af[4], bb[4];
#pragma unroll
    for (int m = 0; m < 4; ++m)
      af[m] = *((const bf16x8*)&Ab[cur][(m * 64 + q * 16 + r) * 8]);
#pragma unroll
    for (int n = 0; n < 4; ++n)
      bb[n] = *((const bf16x8*)&Bb[cur][((w * 4 + n) * 64 + q * 16 + r) * 8]);
#pragma unroll
    for (int m = 0; m < 4; ++m)
#pragma unroll
      for (int n = 0; n < 4; ++n)
        acc[m][n] = __builtin_amdgcn_mfma_f32_16x16x32_bf16(af[m], bb[n], acc[m][n], 0, 0, 0);

    if (ks < 15) {
      // write-late: convert the prefetched A and store to the next buffer
      uint2 pk;
      pk.x = (unsigned)f2bf(xn.x) | ((unsigned)f2bf(xn.y) << 16);
      pk.y = (unsigned)f2bf(xn.z) | ((unsigned)f2bf(xn.w) << 16);
      *((uint2*)&Ab[nxt][ut * 8 + h * 4]) = pk;
    }
    __syncthreads();
  }

  // epilogue: scores partial = sum_col V[col]*tanh(acc + dec_proj[b][col])
  float sp[4][4] = {};
  const float* db = dpj + b * A_;
#pragma unroll
  for (int n = 0; n < 4; ++n) {
    int col = w * 64 + n * 16 + r;
    float vv = V[col];
    float dd = db[col];
#pragma unroll
    for (int m = 0; m < 4; ++m)
#pragma unroll
      for (int j = 0; j < 4; ++j)
        sp[m][j] = fmaf(vv, fast_tanh(acc[m][n][j] + dd), sp[m][j]);
  }
#pragma unroll
  for (int m = 0; m < 4; ++m)
#pragma unroll
    for (int j = 0; j < 4; ++j) {
      float v = sp[m][j];
      v += __shfl_xor(v, 1);
      v += __shfl_xor(v, 2);
      v += __shfl_xor(v, 4);
      v += __shfl_xor(v, 8);
      sp[m][j] = v;
    }
  float outv = 0.f;
#pragma unroll
  for (int mm = 0; mm < 4; ++mm)
#pragma unroll
    for (int jj = 0; jj < 4; ++jj)
      if (r == mm * 4 + jj) outv = sp[mm][jj];
  red[w][(r >> 2) * 16 + q * 4 + (r & 3)] = outv;
  __syncthreads();
  if (tid < 64) {
    float s = 0.f;
#pragma unroll
    for (int ww = 0; ww < 8; ++ww) s += red[ww][tid];
    scores[m0 + tid] = s;
  }
}

// ---------------- K3: softmax over T per b -> weights (output) -------------
__global__ void k_softmax(const float* __restrict__ scores, float* __restrict__ wts) {
  __shared__ float rm[4], rs[4];
  int b = blockIdx.x, tid = threadIdx.x;
  float s[8];
#pragma unroll
  for (int i = 0; i < 8; ++i) s[i] = scores[b * T_ + i * 256 + tid];
  float mx = s[0];
#pragma unroll
  for (int i = 1; i < 8; ++i) mx = fmaxf(mx, s[i]);
#pragma unroll
  for (int off = 1; off <= 32; off <<= 1) mx = fmaxf(mx, __shfl_xor(mx, off));
  if ((tid & 63) == 0) rm[tid >> 6] = mx;
  __syncthreads();
  mx = fmaxf(fmaxf(rm[0], rm[1]), fmaxf(rm[2], rm[3]));
  float ex[8], se = 0.f;
#pragma unroll
  for (int i = 0; i < 8; ++i) { ex[i] = __expf(s[i] - mx); se += ex[i]; }
#pragma unroll
  for (int off = 1; off <= 32; off <<= 1) se += __shfl_xor(se, off);
  if ((tid & 63) == 0) rs[tid >> 6] = se;
  __syncthreads();
  se = rs[0] + rs[1] + rs[2] + rs[3];
  float inv = 1.0f / se;
#pragma unroll
  for (int i = 0; i < 8; ++i) wts[b * T_ + i * 256 + tid] = ex[i] * inv;
}

// ---------------- K4: context partials over 256-t chunks -------------------
__global__ void k_ctx_part(const float* __restrict__ enc, const float* __restrict__ wts,
                           float* __restrict__ part) {
  __shared__ float wl[256];
  __shared__ float4 comb[128];
  int tc = blockIdx.x, b = blockIdx.y;
  int tid = threadIdx.x;
  int t0 = tc * 256;
  wl[tid] = wts[b * T_ + t0 + tid];
  __syncthreads();
  int p = tid >> 7, hq = tid & 127;
  const float* ebase = enc + (size_t)(b * T_ + t0 + p * 128) * H_;
  float ax = 0.f, ay = 0.f, az = 0.f, aw = 0.f;
#pragma unroll 8
  for (int i = 0; i < 128; ++i) {
    float wgt = wl[p * 128 + i];
    float4 x = *((const float4*)(ebase + (size_t)i * H_) + hq);
    ax = fmaf(wgt, x.x, ax);
    ay = fmaf(wgt, x.y, ay);
    az = fmaf(wgt, x.z, az);
    aw = fmaf(wgt, x.w, aw);
  }
  if (p == 1) comb[hq] = make_float4(ax, ay, az, aw);
  __syncthreads();
  if (p == 0) {
    float4 o = comb[hq];
    float4 res = make_float4(ax + o.x, ay + o.y, az + o.z, aw + o.w);
    ((float4*)(part + ((size_t)tc * 64 + b) * H_))[hq] = res;
  }
}

// ---------------- K5: reduce 8 partials -> context (output) ----------------
__global__ void k_ctx_red(const float* __restrict__ part, float* __restrict__ ctx) {
  int idx = blockIdx.x * 256 + threadIdx.x;  // 32768 = B*H
  float s = 0.f;
#pragma unroll
  for (int tc = 0; tc < 8; ++tc) s += part[tc * (B_ * H_) + idx];
  ctx[idx] = s;
}

extern "C" void kernel_launch(void* const* d_in, const int* in_sizes, int n_in,
                              void* d_out, int out_size, void* d_ws, size_t ws_size,
                              hipStream_t stream) {
  const float* enc  = (const float*)d_in[0];
  const float* dec  = (const float*)d_in[1];
  const float* Wenc = (const float*)d_in[2];
  const float* Wdec = (const float*)d_in[3];
  const float* V    = (const float*)d_in[4];
  float* out = (float*)d_out;
  char* ws = (char*)d_ws;

  u16* wsB      = (u16*)ws;                       // 512 KB bf16 tiled W_enc
  float* dpj    = (float*)(ws + 512 * 1024);      // 128 KB dec_proj
  float* scores = (float*)(ws + 640 * 1024);      // 512 KB scores
  float* part   = (float*)(ws + 1152 * 1024);     // 1 MB context partials

  float* ctx = out;            // [B,H] = 32768 floats
  float* wts = out + B_ * H_;  // [B,T] = 131072 floats

  hipLaunchKernelGGL(k_prep, dim3(640), dim3(256), 0, stream, Wenc, wsB, dec, Wdec, dpj);
  hipLaunchKernelGGL(k_scores, dim3(2048), dim3(512), 0, stream, enc, wsB, dpj, V, scores);
  hipLaunchKernelGGL(k_softmax, dim3(64), dim3(256), 0, stream, scores, wts);
  hipLaunchKernelGGL(k_ctx_part, dim3(8, 64), dim3(256), 0, stream, enc, wts, part);
  hipLaunchKernelGGL(k_ctx_red, dim3(128), dim3(256), 0, stream, part, ctx);
}

// Round 3
// 165.152 us; speedup vs baseline: 1.0085x; 1.0085x over previous
//
#include <hip/hip_runtime.h>

#define B_ 64
#define T_ 2048
#define H_ 512
#define A_ 512

typedef unsigned short u16;
typedef __attribute__((ext_vector_type(8))) short bf16x8;
typedef __attribute__((ext_vector_type(4))) float f32x4;

__device__ __forceinline__ u16 f2bf(float f) {
  unsigned u = __float_as_uint(f);
  unsigned r = (u + 0x7FFFu + ((u >> 16) & 1u)) >> 16;  // RNE
  return (u16)r;
}

__device__ __forceinline__ float fast_tanh(float x) {
  float e = __expf(2.0f * x);
  return 1.0f - 2.0f * __builtin_amdgcn_rcpf(e + 1.0f);
}

// ---------------- K1: merged W_enc conversion + dec_proj -------------------
// blocks [0,128): W_enc fp32 -> bf16 fragment-tiled
//   unit idx = ks*2048 + (a>>4)*64 + q*16 + (a&15), holds W_enc[a][ks*32+q*8..+8]
// blocks [128,640): dec_proj[b][a] = dot(dec[b,:], W_dec[a,:])
__global__ void k_prep(const float* __restrict__ W, u16* __restrict__ wsB,
                       const float* __restrict__ dec, const float* __restrict__ Wd,
                       float* __restrict__ dp) {
  __shared__ float dl[H_];
  int tid = threadIdx.x;
  int bx = blockIdx.x;
  if (bx < 128) {
    int u = bx * 256 + tid;  // 32768 units
    int a = u >> 6;
    int hq = u & 63;
    int ks = hq >> 2;
    int q = hq & 3;
    const float4* src = (const float4*)(W + a * H_ + hq * 8);
    float4 x0 = src[0], x1 = src[1];
    uint4 pk;
    pk.x = (unsigned)f2bf(x0.x) | ((unsigned)f2bf(x0.y) << 16);
    pk.y = (unsigned)f2bf(x0.z) | ((unsigned)f2bf(x0.w) << 16);
    pk.z = (unsigned)f2bf(x1.x) | ((unsigned)f2bf(x1.y) << 16);
    pk.w = (unsigned)f2bf(x1.z) | ((unsigned)f2bf(x1.w) << 16);
    int dst = ks * 2048 + (a >> 4) * 64 + q * 16 + (a & 15);
    ((uint4*)wsB)[dst] = pk;
  } else {
    int e = bx - 128;        // 512 blocks
    int b = e >> 3;
    int a0 = (e & 7) * 64;
    dl[tid] = dec[b * H_ + tid];
    dl[tid + 256] = dec[b * H_ + tid + 256];
    __syncthreads();
    int al = tid >> 2, p = tid & 3;
    const float4* wr = (const float4*)(Wd + (a0 + al) * H_ + p * 128);
    const float4* dv = (const float4*)(dl + p * 128);
    float s = 0.f;
#pragma unroll 8
    for (int i = 0; i < 32; ++i) {
      float4 w4 = wr[i], d4 = dv[i];
      s += w4.x * d4.x + w4.y * d4.y + w4.z * d4.z + w4.w * d4.w;
    }
    s += __shfl_xor(s, 1);
    s += __shfl_xor(s, 2);
    if (p == 0) dp[b * H_ + a0 + al] = s;
  }
}

// ---------------- K2: fused enc_proj GEMM + tanh + V-dot -> scores ---------
// BM=128, BN=512. 8 waves; wave w owns cols [w*64, w*64+64) x ALL 128 rows.
// acc = 8 m-frags x 4 n-frags. B fragments read DIRECTLY from L2-resident
// tiled wsB into registers (no LDS, no barrier interaction, 1-step prefetch).
// A staged fp32->bf16 through small double-buffered LDS, one barrier/K-step.
__launch_bounds__(512, 2)
__global__ void k_scores(const float* __restrict__ enc, const u16* __restrict__ wsB,
                         const float* __restrict__ dpj, const float* __restrict__ V,
                         float* __restrict__ scores) {
  __shared__ u16 Ab[2][512 * 8];   // 2 x 8 KB: unit t = row (t>>6)*16+(t&15), k-slot (t>>4)&3
  __shared__ float red[8][128];
  int tid = threadIdx.x;
  int w = tid >> 6, l = tid & 63;
  int q = l >> 4, r = l & 15;
  int m0 = blockIdx.x * 128;
  int b = m0 >> 11;

  f32x4 acc[8][4];
#pragma unroll
  for (int m = 0; m < 8; ++m)
#pragma unroll
    for (int n = 0; n < 4; ++n) acc[m][n] = (f32x4){0.f, 0.f, 0.f, 0.f};

  // A stage addressing: thread t owns unit t (16B = 8 bf16)
  // row = m0 + w*16 + r, k-offset = q*8 (+ ks*32)
  const float* abase = enc + (size_t)(m0 + w * 16 + r) * H_ + q * 8;
  // B fragment base for this lane: unit = ks*2048 + (w*4+n)*64 + l
  const bf16x8* bfrag = (const bf16x8*)wsB;

#define LOAD_B(dst, kss)                                                    \
  {                                                                         \
    _Pragma("unroll") for (int n = 0; n < 4; ++n)                           \
        dst[n] = bfrag[(kss) * 2048 + (w * 4 + n) * 64 + l];                \
  }
#define LOAD_A(y0, y1, kss)                                                 \
  {                                                                         \
    y0 = *((const float4*)(abase + (kss) * 32));                            \
    y1 = *((const float4*)(abase + (kss) * 32 + 4));                        \
  }
#define WRITE_A(buf, y0, y1)                                                \
  {                                                                         \
    uint4 pk;                                                               \
    pk.x = (unsigned)f2bf(y0.x) | ((unsigned)f2bf(y0.y) << 16);             \
    pk.y = (unsigned)f2bf(y0.z) | ((unsigned)f2bf(y0.w) << 16);             \
    pk.z = (unsigned)f2bf(y1.x) | ((unsigned)f2bf(y1.y) << 16);             \
    pk.w = (unsigned)f2bf(y1.z) | ((unsigned)f2bf(y1.w) << 16);             \
    *((uint4*)&Ab[buf][tid * 8]) = pk;                                      \
  }
#define COMPUTE(buf, bb)                                                    \
  {                                                                         \
    bf16x8 af[8];                                                           \
    _Pragma("unroll") for (int m = 0; m < 8; ++m)                           \
        af[m] = *((const bf16x8*)&Ab[buf][(m * 64 + l) * 8]);               \
    _Pragma("unroll") for (int m = 0; m < 8; ++m)                           \
        _Pragma("unroll") for (int n = 0; n < 4; ++n)                       \
            acc[m][n] = __builtin_amdgcn_mfma_f32_16x16x32_bf16(            \
                af[m], bb[n], acc[m][n], 0, 0, 0);                          \
  }

  bf16x8 bbA[4], bbB[4];
  float4 ya0, ya1, yb0, yb1;

  // prologue: stage ks=0
  LOAD_B(bbA, 0);
  LOAD_A(ya0, ya1, 0);
  WRITE_A(0, ya0, ya1);
  __syncthreads();

  for (int i = 0; i < 8; ++i) {
    int ks = 2 * i;
    // ---- part 1: compute ks (Ab[0], bbA); prefetch ks+1 ----
    LOAD_B(bbB, ks + 1);
    LOAD_A(yb0, yb1, ks + 1);
    COMPUTE(0, bbA);
    WRITE_A(1, yb0, yb1);
    __syncthreads();
    // ---- part 2: compute ks+1 (Ab[1], bbB); prefetch ks+2 ----
    if (i < 7) {
      LOAD_B(bbA, ks + 2);
      LOAD_A(ya0, ya1, ks + 2);
    }
    COMPUTE(1, bbB);
    if (i < 7) {
      WRITE_A(0, ya0, ya1);
    }
    __syncthreads();
  }

  // epilogue: per-row partial = sum_cols V[col]*tanh(acc + dec_proj[b][col])
  float sp[8][4];
#pragma unroll
  for (int m = 0; m < 8; ++m)
#pragma unroll
    for (int j = 0; j < 4; ++j) sp[m][j] = 0.f;
  const float* db = dpj + b * A_;
#pragma unroll
  for (int n = 0; n < 4; ++n) {
    int col = w * 64 + n * 16 + r;
    float vv = V[col];
    float dd = db[col];
#pragma unroll
    for (int m = 0; m < 8; ++m)
#pragma unroll
      for (int j = 0; j < 4; ++j)
        sp[m][j] = fmaf(vv, fast_tanh(acc[m][n][j] + dd), sp[m][j]);
  }
  // reduce each sp[m][j] across the 16 lanes (cols) of this quarter-wave
#pragma unroll
  for (int m = 0; m < 8; ++m)
#pragma unroll
    for (int j = 0; j < 4; ++j) {
      float v = sp[m][j];
      v += __shfl_xor(v, 1);
      v += __shfl_xor(v, 2);
      v += __shfl_xor(v, 4);
      v += __shfl_xor(v, 8);
      sp[m][j] = v;
    }
  // lane r writes rows for (m,j) with m*4+j == r and == r+16
  float o0 = 0.f, o1 = 0.f;
  int mA = r >> 2, jA = r & 3;          // m*4+j == r  (m<4)
  int mB = mA + 4, jB = jA;             // m*4+j == r+16
#pragma unroll
  for (int mm = 0; mm < 8; ++mm)
#pragma unroll
    for (int jj = 0; jj < 4; ++jj) {
      if (mm == mA && jj == jA) o0 = sp[mm][jj];
      if (mm == mB && jj == jB) o1 = sp[mm][jj];
    }
  red[w][mA * 16 + q * 4 + jA] = o0;
  red[w][mB * 16 + q * 4 + jB] = o1;
  __syncthreads();
  if (tid < 128) {
    float s = 0.f;
#pragma unroll
    for (int ww = 0; ww < 8; ++ww) s += red[ww][tid];
    scores[m0 + tid] = s;
  }
#undef LOAD_B
#undef LOAD_A
#undef WRITE_A
#undef COMPUTE
}

// ---------------- K3: softmax over T per b -> weights (output) -------------
__global__ void k_softmax(const float* __restrict__ scores, float* __restrict__ wts) {
  __shared__ float rm[4], rs[4];
  int b = blockIdx.x, tid = threadIdx.x;
  float s[8];
#pragma unroll
  for (int i = 0; i < 8; ++i) s[i] = scores[b * T_ + i * 256 + tid];
  float mx = s[0];
#pragma unroll
  for (int i = 1; i < 8; ++i) mx = fmaxf(mx, s[i]);
#pragma unroll
  for (int off = 1; off <= 32; off <<= 1) mx = fmaxf(mx, __shfl_xor(mx, off));
  if ((tid & 63) == 0) rm[tid >> 6] = mx;
  __syncthreads();
  mx = fmaxf(fmaxf(rm[0], rm[1]), fmaxf(rm[2], rm[3]));
  float ex[8], se = 0.f;
#pragma unroll
  for (int i = 0; i < 8; ++i) { ex[i] = __expf(s[i] - mx); se += ex[i]; }
#pragma unroll
  for (int off = 1; off <= 32; off <<= 1) se += __shfl_xor(se, off);
  if ((tid & 63) == 0) rs[tid >> 6] = se;
  __syncthreads();
  se = rs[0] + rs[1] + rs[2] + rs[3];
  float inv = 1.0f / se;
#pragma unroll
  for (int i = 0; i < 8; ++i) wts[b * T_ + i * 256 + tid] = ex[i] * inv;
}

// ---------------- K4: context partials over 256-t chunks -------------------
__global__ void k_ctx_part(const float* __restrict__ enc, const float* __restrict__ wts,
                           float* __restrict__ part) {
  __shared__ float wl[256];
  __shared__ float4 comb[128];
  int tc = blockIdx.x, b = blockIdx.y;
  int tid = threadIdx.x;
  int t0 = tc * 256;
  wl[tid] = wts[b * T_ + t0 + tid];
  __syncthreads();
  int p = tid >> 7, hq = tid & 127;
  const float* ebase = enc + (size_t)(b * T_ + t0 + p * 128) * H_;
  float ax = 0.f, ay = 0.f, az = 0.f, aw = 0.f;
#pragma unroll 8
  for (int i = 0; i < 128; ++i) {
    float wgt = wl[p * 128 + i];
    float4 x = *((const float4*)(ebase + (size_t)i * H_) + hq);
    ax = fmaf(wgt, x.x, ax);
    ay = fmaf(wgt, x.y, ay);
    az = fmaf(wgt, x.z, az);
    aw = fmaf(wgt, x.w, aw);
  }
  if (p == 1) comb[hq] = make_float4(ax, ay, az, aw);
  __syncthreads();
  if (p == 0) {
    float4 o = comb[hq];
    float4 res = make_float4(ax + o.x, ay + o.y, az + o.z, aw + o.w);
    ((float4*)(part + ((size_t)tc * 64 + b) * H_))[hq] = res;
  }
}

// ---------------- K5: reduce 8 partials -> context (output) ----------------
__global__ void k_ctx_red(const float* __restrict__ part, float* __restrict__ ctx) {
  int idx = blockIdx.x * 256 + threadIdx.x;  // 32768 = B*H
  float s = 0.f;
#pragma unroll
  for (int tc = 0; tc < 8; ++tc) s += part[tc * (B_ * H_) + idx];
  ctx[idx] = s;
}

extern "C" void kernel_launch(void* const* d_in, const int* in_sizes, int n_in,
                              void* d_out, int out_size, void* d_ws, size_t ws_size,
                              hipStream_t stream) {
  const float* enc  = (const float*)d_in[0];
  const float* dec  = (const float*)d_in[1];
  const float* Wenc = (const float*)d_in[2];
  const float* Wdec = (const float*)d_in[3];
  const float* V    = (const float*)d_in[4];
  float* out = (float*)d_out;
  char* ws = (char*)d_ws;

  u16* wsB      = (u16*)ws;                       // 512 KB bf16 tiled W_enc
  float* dpj    = (float*)(ws + 512 * 1024);      // 128 KB dec_proj
  float* scores = (float*)(ws + 640 * 1024);      // 512 KB scores
  float* part   = (float*)(ws + 1152 * 1024);     // 1 MB context partials

  float* ctx = out;            // [B,H] = 32768 floats
  float* wts = out + B_ * H_;  // [B,T] = 131072 floats

  hipLaunchKernelGGL(k_prep, dim3(640), dim3(256), 0, stream, Wenc, wsB, dec, Wdec, dpj);
  hipLaunchKernelGGL(k_scores, dim3(1024), dim3(512), 0, stream, enc, wsB, dpj, V, scores);
  hipLaunchKernelGGL(k_softmax, dim3(64), dim3(256), 0, stream, scores, wts);
  hipLaunchKernelGGL(k_ctx_part, dim3(8, 64), dim3(256), 0, stream, enc, wts, part);
  hipLaunchKernelGGL(k_ctx_red, dim3(128), dim3(256), 0, stream, part, ctx);
}

// Round 4
// 149.674 us; speedup vs baseline: 1.1128x; 1.1034x over previous
//
#include <hip/hip_runtime.h>

#define B_ 64
#define T_ 2048
#define H_ 512
#define A_ 512

typedef unsigned short u16;
typedef __attribute__((ext_vector_type(8))) short bf16x8;
typedef __attribute__((ext_vector_type(4))) float f32x4;

__device__ __forceinline__ u16 f2bf(float f) {
  unsigned u = __float_as_uint(f);
  unsigned r = (u + 0x7FFFu + ((u >> 16) & 1u)) >> 16;  // RNE
  return (u16)r;
}

__device__ __forceinline__ float fast_tanh(float x) {
  float e = __expf(2.0f * x);
  return 1.0f - 2.0f * __builtin_amdgcn_rcpf(e + 1.0f);
}

// ---------------- K1: merged W_enc conversion + dec_proj -------------------
// blocks [0,128): W_enc fp32 -> bf16 fragment-tiled
//   unit idx = ks*2048 + (a>>4)*64 + q*16 + (a&15), holds W_enc[a][ks*32+q*8..+8]
// blocks [128,640): dec_proj[b][a] = dot(dec[b,:], W_dec[a,:])
__global__ void k_prep(const float* __restrict__ W, u16* __restrict__ wsB,
                       const float* __restrict__ dec, const float* __restrict__ Wd,
                       float* __restrict__ dp) {
  __shared__ float dl[H_];
  int tid = threadIdx.x;
  int bx = blockIdx.x;
  if (bx < 128) {
    int u = bx * 256 + tid;  // 32768 units
    int a = u >> 6;
    int hq = u & 63;
    int ks = hq >> 2;
    int q = hq & 3;
    const float4* src = (const float4*)(W + a * H_ + hq * 8);
    float4 x0 = src[0], x1 = src[1];
    uint4 pk;
    pk.x = (unsigned)f2bf(x0.x) | ((unsigned)f2bf(x0.y) << 16);
    pk.y = (unsigned)f2bf(x0.z) | ((unsigned)f2bf(x0.w) << 16);
    pk.z = (unsigned)f2bf(x1.x) | ((unsigned)f2bf(x1.y) << 16);
    pk.w = (unsigned)f2bf(x1.z) | ((unsigned)f2bf(x1.w) << 16);
    int dst = ks * 2048 + (a >> 4) * 64 + q * 16 + (a & 15);
    ((uint4*)wsB)[dst] = pk;
  } else {
    int e = bx - 128;        // 512 blocks
    int b = e >> 3;
    int a0 = (e & 7) * 64;
    dl[tid] = dec[b * H_ + tid];
    dl[tid + 256] = dec[b * H_ + tid + 256];
    __syncthreads();
    int al = tid >> 2, p = tid & 3;
    const float4* wr = (const float4*)(Wd + (a0 + al) * H_ + p * 128);
    const float4* dv = (const float4*)(dl + p * 128);
    float s = 0.f;
#pragma unroll 8
    for (int i = 0; i < 32; ++i) {
      float4 w4 = wr[i], d4 = dv[i];
      s += w4.x * d4.x + w4.y * d4.y + w4.z * d4.z + w4.w * d4.w;
    }
    s += __shfl_xor(s, 1);
    s += __shfl_xor(s, 2);
    if (p == 0) dp[b * H_ + a0 + al] = s;
  }
}

// ---------------- K2: fused enc_proj GEMM + tanh + V-dot -> scores ---------
// BM=64, BN=512, 8 waves; wave w owns cols [w*64, w*64+64).
// Whole A-tile (64x512 bf16 = 64 KB) staged ONCE into LDS (fragment-tiled),
// then 16 K-steps of BARRIER-FREE compute: A via linear ds_read_b128,
// B fragments straight from L2-resident tiled wsB into registers.
// LDS unit u (16B, 8 bf16) = ks*256 + m*64 + q*16 + r
//   holds enc_bf16[row = m*16+r][cols ks*32+q*8 .. +8]
__launch_bounds__(512, 4)
__global__ void k_scores(const float* __restrict__ enc, const u16* __restrict__ wsB,
                         const float* __restrict__ dpj, const float* __restrict__ V,
                         float* __restrict__ scores) {
  __shared__ u16 Ab[64 * 512];   // exactly 64 KB
  int tid = threadIdx.x;
  int w = tid >> 6, l = tid & 63;
  int q = l >> 4, r = l & 15;
  int m0 = blockIdx.x * 64;
  int b = m0 >> 11;

  // ---- stage whole A-tile: 16 x 32B burst loads per thread, one drain ----
  // thread's fixed unit decode: rem = tid&255 -> m,q,r ; ks = it*2 + (tid>>8)
  {
    int rem = tid & 255;
    int sm = rem >> 6, sq = (rem >> 4) & 3, sr = rem & 15;
    const float* ab = enc + (size_t)(m0 + sm * 16 + sr) * H_ + (tid >> 8) * 32 + sq * 8;
    float4 x0[8], x1[8];
#pragma unroll
    for (int it = 0; it < 8; ++it) {
      x0[it] = *((const float4*)(ab + it * 64));
      x1[it] = *((const float4*)(ab + it * 64 + 4));
    }
#pragma unroll
    for (int it = 0; it < 8; ++it) {
      uint4 pk;
      pk.x = (unsigned)f2bf(x0[it].x) | ((unsigned)f2bf(x0[it].y) << 16);
      pk.y = (unsigned)f2bf(x0[it].z) | ((unsigned)f2bf(x0[it].w) << 16);
      pk.z = (unsigned)f2bf(x1[it].x) | ((unsigned)f2bf(x1[it].y) << 16);
      pk.w = (unsigned)f2bf(x1[it].z) | ((unsigned)f2bf(x1[it].w) << 16);
      ((uint4*)Ab)[it * 512 + tid] = pk;
    }
  }
  __syncthreads();

  f32x4 acc[4][4];
#pragma unroll
  for (int m = 0; m < 4; ++m)
#pragma unroll
    for (int n = 0; n < 4; ++n) acc[m][n] = (f32x4){0.f, 0.f, 0.f, 0.f};

  const bf16x8* bfrag = (const bf16x8*)wsB;

  // ---- barrier-free K loop ----
  for (int ks = 0; ks < 16; ++ks) {
    bf16x8 bb[4], af[4];
#pragma unroll
    for (int n = 0; n < 4; ++n)
      bb[n] = bfrag[ks * 2048 + (w * 4 + n) * 64 + l];
#pragma unroll
    for (int m = 0; m < 4; ++m)
      af[m] = *((const bf16x8*)&Ab[(ks * 256 + m * 64 + l) * 8]);
    __builtin_amdgcn_s_setprio(1);
#pragma unroll
    for (int m = 0; m < 4; ++m)
#pragma unroll
      for (int n = 0; n < 4; ++n)
        acc[m][n] = __builtin_amdgcn_mfma_f32_16x16x32_bf16(af[m], bb[n], acc[m][n], 0, 0, 0);
    __builtin_amdgcn_s_setprio(0);
  }

  // epilogue: per-row partial = sum_cols V[col]*tanh(acc + dec_proj[b][col])
  float sp[4][4] = {};
  const float* db = dpj + b * A_;
#pragma unroll
  for (int n = 0; n < 4; ++n) {
    int col = w * 64 + n * 16 + r;
    float vv = V[col];
    float dd = db[col];
#pragma unroll
    for (int m = 0; m < 4; ++m)
#pragma unroll
      for (int j = 0; j < 4; ++j)
        sp[m][j] = fmaf(vv, fast_tanh(acc[m][n][j] + dd), sp[m][j]);
  }
#pragma unroll
  for (int m = 0; m < 4; ++m)
#pragma unroll
    for (int j = 0; j < 4; ++j) {
      float v = sp[m][j];
      v += __shfl_xor(v, 1);
      v += __shfl_xor(v, 2);
      v += __shfl_xor(v, 4);
      v += __shfl_xor(v, 8);
      sp[m][j] = v;
    }
  float outv = 0.f;
#pragma unroll
  for (int mm = 0; mm < 4; ++mm)
#pragma unroll
    for (int jj = 0; jj < 4; ++jj)
      if (r == mm * 4 + jj) outv = sp[mm][jj];
  // alias reduction scratch onto Ab (all A reads are done; barrier protects)
  float* red = (float*)Ab;
  __syncthreads();
  red[w * 64 + (r >> 2) * 16 + q * 4 + (r & 3)] = outv;
  __syncthreads();
  if (tid < 64) {
    float s = 0.f;
#pragma unroll
    for (int ww = 0; ww < 8; ++ww) s += red[ww * 64 + tid];
    scores[m0 + tid] = s;
  }
}

// ---------------- K3: softmax over T per b -> weights (output) -------------
__global__ void k_softmax(const float* __restrict__ scores, float* __restrict__ wts) {
  __shared__ float rm[4], rs[4];
  int b = blockIdx.x, tid = threadIdx.x;
  float s[8];
#pragma unroll
  for (int i = 0; i < 8; ++i) s[i] = scores[b * T_ + i * 256 + tid];
  float mx = s[0];
#pragma unroll
  for (int i = 1; i < 8; ++i) mx = fmaxf(mx, s[i]);
#pragma unroll
  for (int off = 1; off <= 32; off <<= 1) mx = fmaxf(mx, __shfl_xor(mx, off));
  if ((tid & 63) == 0) rm[tid >> 6] = mx;
  __syncthreads();
  mx = fmaxf(fmaxf(rm[0], rm[1]), fmaxf(rm[2], rm[3]));
  float ex[8], se = 0.f;
#pragma unroll
  for (int i = 0; i < 8; ++i) { ex[i] = __expf(s[i] - mx); se += ex[i]; }
#pragma unroll
  for (int off = 1; off <= 32; off <<= 1) se += __shfl_xor(se, off);
  if ((tid & 63) == 0) rs[tid >> 6] = se;
  __syncthreads();
  se = rs[0] + rs[1] + rs[2] + rs[3];
  float inv = 1.0f / se;
#pragma unroll
  for (int i = 0; i < 8; ++i) wts[b * T_ + i * 256 + tid] = ex[i] * inv;
}

// ---------------- K4: context partials over 256-t chunks -------------------
__global__ void k_ctx_part(const float* __restrict__ enc, const float* __restrict__ wts,
                           float* __restrict__ part) {
  __shared__ float wl[256];
  __shared__ float4 comb[128];
  int tc = blockIdx.x, b = blockIdx.y;
  int tid = threadIdx.x;
  int t0 = tc * 256;
  wl[tid] = wts[b * T_ + t0 + tid];
  __syncthreads();
  int p = tid >> 7, hq = tid & 127;
  const float* ebase = enc + (size_t)(b * T_ + t0 + p * 128) * H_;
  float ax = 0.f, ay = 0.f, az = 0.f, aw = 0.f;
#pragma unroll 8
  for (int i = 0; i < 128; ++i) {
    float wgt = wl[p * 128 + i];
    float4 x = *((const float4*)(ebase + (size_t)i * H_) + hq);
    ax = fmaf(wgt, x.x, ax);
    ay = fmaf(wgt, x.y, ay);
    az = fmaf(wgt, x.z, az);
    aw = fmaf(wgt, x.w, aw);
  }
  if (p == 1) comb[hq] = make_float4(ax, ay, az, aw);
  __syncthreads();
  if (p == 0) {
    float4 o = comb[hq];
    float4 res = make_float4(ax + o.x, ay + o.y, az + o.z, aw + o.w);
    ((float4*)(part + ((size_t)tc * 64 + b) * H_))[hq] = res;
  }
}

// ---------------- K5: reduce 8 partials -> context (output) ----------------
__global__ void k_ctx_red(const float* __restrict__ part, float* __restrict__ ctx) {
  int idx = blockIdx.x * 256 + threadIdx.x;  // 32768 = B*H
  float s = 0.f;
#pragma unroll
  for (int tc = 0; tc < 8; ++tc) s += part[tc * (B_ * H_) + idx];
  ctx[idx] = s;
}

extern "C" void kernel_launch(void* const* d_in, const int* in_sizes, int n_in,
                              void* d_out, int out_size, void* d_ws, size_t ws_size,
                              hipStream_t stream) {
  const float* enc  = (const float*)d_in[0];
  const float* dec  = (const float*)d_in[1];
  const float* Wenc = (const float*)d_in[2];
  const float* Wdec = (const float*)d_in[3];
  const float* V    = (const float*)d_in[4];
  float* out = (float*)d_out;
  char* ws = (char*)d_ws;

  u16* wsB      = (u16*)ws;                       // 512 KB bf16 tiled W_enc
  float* dpj    = (float*)(ws + 512 * 1024);      // 128 KB dec_proj
  float* scores = (float*)(ws + 640 * 1024);      // 512 KB scores
  float* part   = (float*)(ws + 1152 * 1024);     // 1 MB context partials

  float* ctx = out;            // [B,H] = 32768 floats
  float* wts = out + B_ * H_;  // [B,T] = 131072 floats

  hipLaunchKernelGGL(k_prep, dim3(640), dim3(256), 0, stream, Wenc, wsB, dec, Wdec, dpj);
  hipLaunchKernelGGL(k_scores, dim3(2048), dim3(512), 0, stream, enc, wsB, dpj, V, scores);
  hipLaunchKernelGGL(k_softmax, dim3(64), dim3(256), 0, stream, scores, wts);
  hipLaunchKernelGGL(k_ctx_part, dim3(8, 64), dim3(256), 0, stream, enc, wts, part);
  hipLaunchKernelGGL(k_ctx_red, dim3(128), dim3(256), 0, stream, part, ctx);
}

// Round 5
// 122.784 us; speedup vs baseline: 1.3565x; 1.2190x over previous
//
#include <hip/hip_runtime.h>

#define B_ 64
#define T_ 2048
#define H_ 512
#define A_ 512

typedef unsigned short u16;
typedef __attribute__((ext_vector_type(8))) short bf16x8;
typedef __attribute__((ext_vector_type(4))) float f32x4;

__device__ __forceinline__ u16 f2bf(float f) {
  unsigned u = __float_as_uint(f);
  unsigned r = (u + 0x7FFFu + ((u >> 16) & 1u)) >> 16;  // RNE
  return (u16)r;
}

__device__ __forceinline__ float bf2f(u16 h) {
  return __uint_as_float(((unsigned)h) << 16);
}

__device__ __forceinline__ float fast_tanh(float x) {
  float e = __expf(2.0f * x);
  return 1.0f - 2.0f * __builtin_amdgcn_rcpf(e + 1.0f);
}

// ---------------- K1: merged W_enc conversion + dec_proj -------------------
// blocks [0,128): W_enc fp32 -> bf16 fragment-tiled
//   unit idx = ks*2048 + (a>>4)*64 + q*16 + (a&15), holds W_enc[a][ks*32+q*8..+8]
// blocks [128,640): dec_proj[b][a] = dot(dec[b,:], W_dec[a,:])
__global__ void k_prep(const float* __restrict__ W, u16* __restrict__ wsB,
                       const float* __restrict__ dec, const float* __restrict__ Wd,
                       float* __restrict__ dp) {
  __shared__ float dl[H_];
  int tid = threadIdx.x;
  int bx = blockIdx.x;
  if (bx < 128) {
    int u = bx * 256 + tid;  // 32768 units
    int a = u >> 6;
    int hq = u & 63;
    int ks = hq >> 2;
    int q = hq & 3;
    const float4* src = (const float4*)(W + a * H_ + hq * 8);
    float4 x0 = src[0], x1 = src[1];
    uint4 pk;
    pk.x = (unsigned)f2bf(x0.x) | ((unsigned)f2bf(x0.y) << 16);
    pk.y = (unsigned)f2bf(x0.z) | ((unsigned)f2bf(x0.w) << 16);
    pk.z = (unsigned)f2bf(x1.x) | ((unsigned)f2bf(x1.y) << 16);
    pk.w = (unsigned)f2bf(x1.z) | ((unsigned)f2bf(x1.w) << 16);
    int dst = ks * 2048 + (a >> 4) * 64 + q * 16 + (a & 15);
    ((uint4*)wsB)[dst] = pk;
  } else {
    int e = bx - 128;        // 512 blocks
    int b = e >> 3;
    int a0 = (e & 7) * 64;
    dl[tid] = dec[b * H_ + tid];
    dl[tid + 256] = dec[b * H_ + tid + 256];
    __syncthreads();
    int al = tid >> 2, p = tid & 3;
    const float4* wr = (const float4*)(Wd + (a0 + al) * H_ + p * 128);
    const float4* dv = (const float4*)(dl + p * 128);
    float s = 0.f;
#pragma unroll 8
    for (int i = 0; i < 32; ++i) {
      float4 w4 = wr[i], d4 = dv[i];
      s += w4.x * d4.x + w4.y * d4.y + w4.z * d4.z + w4.w * d4.w;
    }
    s += __shfl_xor(s, 1);
    s += __shfl_xor(s, 2);
    if (p == 0) dp[b * H_ + a0 + al] = s;
  }
}

// ---------------- K2: fused GEMM + tanh + V-dot + local softmax + PV -------
// BM=64, BN=512, 8 waves; wave w owns cols [w*64, w*64+64).
// A-tile (64x512 bf16 = 64 KB) staged in 4 chunks (4 K-steps each), chunk c+1
// loads issued before chunk c's MFMAs, converted+written after (T14/T3).
// Epilogue: scores + block-local softmax (m_loc, Z) + partial context from
// the LDS A-tile (flash-style; recombined in k_ctx_comb).
// LDS unit u (16B, 8 bf16) = ks*256 + m*64 + q*16 + r
//   holds enc_bf16[row = m*16+r][cols ks*32+q*8 .. +8]
__launch_bounds__(512, 4)
__global__ void k_scores(const float* __restrict__ enc, const u16* __restrict__ wsB,
                         const float* __restrict__ dpj, const float* __restrict__ V,
                         float* __restrict__ scores, float* __restrict__ part,
                         float* __restrict__ mz) {
  __shared__ __attribute__((aligned(16))) u16 Ab[64 * 512];  // 64 KB
  __shared__ float red[8][64];
  __shared__ float e_lds[64];
  int tid = threadIdx.x;
  int w = tid >> 6, l = tid & 63;
  int q = l >> 4, r = l & 15;
  int m0 = blockIdx.x * 64;
  int b = m0 >> 11;

  // staging decode: thread owns unit it*512+tid for it=0..7
  // row = sm*16+sr, cols = (tid>>8)*32 + sq*8 + it*64  (ks = it*2 + (tid>>8))
  int rem = tid & 255;
  int sm = rem >> 6, sq = (rem >> 4) & 3, sr = rem & 15;
  const float* ab = enc + (size_t)(m0 + sm * 16 + sr) * H_ + (tid >> 8) * 32 + sq * 8;

#define STG_WRITE(y0, y1, it)                                         \
  {                                                                   \
    uint4 pk;                                                         \
    pk.x = (unsigned)f2bf(y0.x) | ((unsigned)f2bf(y0.y) << 16);       \
    pk.y = (unsigned)f2bf(y0.z) | ((unsigned)f2bf(y0.w) << 16);       \
    pk.z = (unsigned)f2bf(y1.x) | ((unsigned)f2bf(y1.y) << 16);       \
    pk.w = (unsigned)f2bf(y1.z) | ((unsigned)f2bf(y1.w) << 16);       \
    ((uint4*)Ab)[(it) * 512 + tid] = pk;                              \
  }

  f32x4 acc[4][4];
#pragma unroll
  for (int m = 0; m < 4; ++m)
#pragma unroll
    for (int n = 0; n < 4; ++n) acc[m][n] = (f32x4){0.f, 0.f, 0.f, 0.f};

  const bf16x8* bfrag = (const bf16x8*)wsB;

  // prologue: stage chunk 0 (it = 0,1 -> ks 0..3)
  {
    float4 y0 = *((const float4*)(ab + 0));
    float4 y1 = *((const float4*)(ab + 4));
    float4 y2 = *((const float4*)(ab + 64));
    float4 y3 = *((const float4*)(ab + 68));
    STG_WRITE(y0, y1, 0)
    STG_WRITE(y2, y3, 1)
  }
  __syncthreads();

#pragma unroll
  for (int c = 0; c < 4; ++c) {
    float4 y0, y1, y2, y3;
    if (c < 3) {  // issue next chunk's loads early (T14)
      y0 = *((const float4*)(ab + (2 * c + 2) * 64));
      y1 = *((const float4*)(ab + (2 * c + 2) * 64 + 4));
      y2 = *((const float4*)(ab + (2 * c + 3) * 64));
      y3 = *((const float4*)(ab + (2 * c + 3) * 64 + 4));
    }
#pragma unroll
    for (int kk = 0; kk < 4; ++kk) {
      int ks = c * 4 + kk;
      bf16x8 bb[4], af[4];
#pragma unroll
      for (int n = 0; n < 4; ++n)
        bb[n] = bfrag[ks * 2048 + (w * 4 + n) * 64 + l];
#pragma unroll
      for (int m = 0; m < 4; ++m)
        af[m] = *((const bf16x8*)&Ab[(ks * 256 + m * 64 + l) * 8]);
      __builtin_amdgcn_s_setprio(1);
#pragma unroll
      for (int m = 0; m < 4; ++m)
#pragma unroll
        for (int n = 0; n < 4; ++n)
          acc[m][n] = __builtin_amdgcn_mfma_f32_16x16x32_bf16(af[m], bb[n], acc[m][n], 0, 0, 0);
      __builtin_amdgcn_s_setprio(0);
    }
    if (c < 3) {  // write-late: convert prefetched A into next chunk
      STG_WRITE(y0, y1, 2 * c + 2)
      STG_WRITE(y2, y3, 2 * c + 3)
    }
    __syncthreads();
  }

  // ---- scores epilogue: sp = sum_cols V[col]*tanh(acc + dec_proj) ----
  float sp[4][4] = {};
  const float* db = dpj + b * A_;
#pragma unroll
  for (int n = 0; n < 4; ++n) {
    int col = w * 64 + n * 16 + r;
    float vv = V[col];
    float dd = db[col];
#pragma unroll
    for (int m = 0; m < 4; ++m)
#pragma unroll
      for (int j = 0; j < 4; ++j)
        sp[m][j] = fmaf(vv, fast_tanh(acc[m][n][j] + dd), sp[m][j]);
  }
#pragma unroll
  for (int m = 0; m < 4; ++m)
#pragma unroll
    for (int j = 0; j < 4; ++j) {
      float v = sp[m][j];
      v += __shfl_xor(v, 1);
      v += __shfl_xor(v, 2);
      v += __shfl_xor(v, 4);
      v += __shfl_xor(v, 8);
      sp[m][j] = v;
    }
  float outv = 0.f;
#pragma unroll
  for (int mm = 0; mm < 4; ++mm)
#pragma unroll
    for (int jj = 0; jj < 4; ++jj)
      if (r == mm * 4 + jj) outv = sp[mm][jj];
  red[w][(r >> 2) * 16 + q * 4 + (r & 3)] = outv;
  __syncthreads();

  // ---- wave 0: final scores + local softmax (m_loc, Z, e_row) ----
  if (tid < 64) {
    float s = 0.f;
#pragma unroll
    for (int ww = 0; ww < 8; ++ww) s += red[ww][tid];
    scores[m0 + tid] = s;
    float mx = s;
#pragma unroll
    for (int off = 1; off <= 32; off <<= 1) mx = fmaxf(mx, __shfl_xor(mx, off));
    float e = __expf(s - mx);
    float Z = e;
#pragma unroll
    for (int off = 1; off <= 32; off <<= 1) Z += __shfl_xor(Z, off);
    e_lds[tid] = e;
    if (tid == 0) {
      mz[blockIdx.x * 2] = mx;
      mz[blockIdx.x * 2 + 1] = Z;
    }
  }
  __syncthreads();

  // ---- PV: partial ctx[col] = sum_rows e_row * enc_bf16[row][col] ----
  // wave w covers ks = 2w, 2w+1 (cols w*64 .. w*64+64); af-style reads.
  {
    float pv0[8], pv1[8];
#pragma unroll
    for (int j = 0; j < 8; ++j) { pv0[j] = 0.f; pv1[j] = 0.f; }
#pragma unroll
    for (int ksl = 0; ksl < 2; ++ksl) {
      int ks = 2 * w + ksl;
#pragma unroll
      for (int m = 0; m < 4; ++m) {
        uint4 pk = ((const uint4*)Ab)[ks * 256 + m * 64 + l];
        float er = e_lds[m * 16 + r];
        float v0 = bf2f((u16)(pk.x & 0xffff)), v1 = bf2f((u16)(pk.x >> 16));
        float v2 = bf2f((u16)(pk.y & 0xffff)), v3 = bf2f((u16)(pk.y >> 16));
        float v4 = bf2f((u16)(pk.z & 0xffff)), v5 = bf2f((u16)(pk.z >> 16));
        float v6 = bf2f((u16)(pk.w & 0xffff)), v7 = bf2f((u16)(pk.w >> 16));
        if (ksl == 0) {
          pv0[0] = fmaf(er, v0, pv0[0]); pv0[1] = fmaf(er, v1, pv0[1]);
          pv0[2] = fmaf(er, v2, pv0[2]); pv0[3] = fmaf(er, v3, pv0[3]);
          pv0[4] = fmaf(er, v4, pv0[4]); pv0[5] = fmaf(er, v5, pv0[5]);
          pv0[6] = fmaf(er, v6, pv0[6]); pv0[7] = fmaf(er, v7, pv0[7]);
        } else {
          pv1[0] = fmaf(er, v0, pv1[0]); pv1[1] = fmaf(er, v1, pv1[1]);
          pv1[2] = fmaf(er, v2, pv1[2]); pv1[3] = fmaf(er, v3, pv1[3]);
          pv1[4] = fmaf(er, v4, pv1[4]); pv1[5] = fmaf(er, v5, pv1[5]);
          pv1[6] = fmaf(er, v6, pv1[6]); pv1[7] = fmaf(er, v7, pv1[7]);
        }
      }
    }
    // reduce over the 16 row-lanes of each quadrant
#pragma unroll
    for (int j = 0; j < 8; ++j) {
      float a0 = pv0[j], a1 = pv1[j];
      a0 += __shfl_xor(a0, 1); a1 += __shfl_xor(a1, 1);
      a0 += __shfl_xor(a0, 2); a1 += __shfl_xor(a1, 2);
      a0 += __shfl_xor(a0, 4); a1 += __shfl_xor(a1, 4);
      a0 += __shfl_xor(a0, 8); a1 += __shfl_xor(a1, 8);
      pv0[j] = a0; pv1[j] = a1;
    }
    // lane (q,r) writes col w*64 + (r>>3)*32 + q*8 + (r&7)
    float ov = 0.f;
#pragma unroll
    for (int jj = 0; jj < 8; ++jj) {
      if (r == jj) ov = pv0[jj];
      if (r == jj + 8) ov = pv1[jj];
    }
    int col = w * 64 + (r >> 3) * 32 + q * 8 + (r & 7);
    part[(size_t)blockIdx.x * 512 + col] = ov;
  }
#undef STG_WRITE
}

// ---------------- K3: softmax over T per b -> weights (output) -------------
__global__ void k_softmax(const float* __restrict__ scores, float* __restrict__ wts) {
  __shared__ float rm[4], rs[4];
  int b = blockIdx.x, tid = threadIdx.x;
  float s[8];
#pragma unroll
  for (int i = 0; i < 8; ++i) s[i] = scores[b * T_ + i * 256 + tid];
  float mx = s[0];
#pragma unroll
  for (int i = 1; i < 8; ++i) mx = fmaxf(mx, s[i]);
#pragma unroll
  for (int off = 1; off <= 32; off <<= 1) mx = fmaxf(mx, __shfl_xor(mx, off));
  if ((tid & 63) == 0) rm[tid >> 6] = mx;
  __syncthreads();
  mx = fmaxf(fmaxf(rm[0], rm[1]), fmaxf(rm[2], rm[3]));
  float ex[8], se = 0.f;
#pragma unroll
  for (int i = 0; i < 8; ++i) { ex[i] = __expf(s[i] - mx); se += ex[i]; }
#pragma unroll
  for (int off = 1; off <= 32; off <<= 1) se += __shfl_xor(se, off);
  if ((tid & 63) == 0) rs[tid >> 6] = se;
  __syncthreads();
  se = rs[0] + rs[1] + rs[2] + rs[3];
  float inv = 1.0f / se;
#pragma unroll
  for (int i = 0; i < 8; ++i) wts[b * T_ + i * 256 + tid] = ex[i] * inv;
}

// ---------------- K4: flash recombine partial contexts -> context ----------
__global__ void k_ctx_comb(const float* __restrict__ part, const float* __restrict__ mz,
                           float* __restrict__ ctx) {
  __shared__ float sM[32], sZ[32];
  int b = blockIdx.x, tid = threadIdx.x;  // 512 threads, thread = h
  if (tid < 32) {
    sM[tid] = mz[(b * 32 + tid) * 2];
    sZ[tid] = mz[(b * 32 + tid) * 2 + 1];
  }
  __syncthreads();
  float M = sM[0];
#pragma unroll
  for (int i = 1; i < 32; ++i) M = fmaxf(M, sM[i]);
  float denom = 0.f;
#pragma unroll
  for (int i = 0; i < 32; ++i) denom += sZ[i] * __expf(sM[i] - M);
  float s = 0.f;
#pragma unroll
  for (int i = 0; i < 32; ++i)
    s += part[((size_t)b * 32 + i) * 512 + tid] * __expf(sM[i] - M);
  ctx[b * 512 + tid] = s / denom;
}

extern "C" void kernel_launch(void* const* d_in, const int* in_sizes, int n_in,
                              void* d_out, int out_size, void* d_ws, size_t ws_size,
                              hipStream_t stream) {
  const float* enc  = (const float*)d_in[0];
  const float* dec  = (const float*)d_in[1];
  const float* Wenc = (const float*)d_in[2];
  const float* Wdec = (const float*)d_in[3];
  const float* V    = (const float*)d_in[4];
  float* out = (float*)d_out;
  char* ws = (char*)d_ws;

  u16* wsB      = (u16*)ws;                            // 512 KB bf16 tiled W_enc
  float* dpj    = (float*)(ws + 512 * 1024);           // 128 KB dec_proj
  float* scores = (float*)(ws + 640 * 1024);           // 512 KB scores
  float* part   = (float*)(ws + 1152 * 1024);          // 4 MB ctx partials (2048 x 512)
  float* mz     = (float*)(ws + 1152 * 1024 + 4 * 1024 * 1024);  // 16 KB (m,Z)

  float* ctx = out;            // [B,H] = 32768 floats
  float* wts = out + B_ * H_;  // [B,T] = 131072 floats

  hipLaunchKernelGGL(k_prep, dim3(640), dim3(256), 0, stream, Wenc, wsB, dec, Wdec, dpj);
  hipLaunchKernelGGL(k_scores, dim3(2048), dim3(512), 0, stream, enc, wsB, dpj, V,
                     scores, part, mz);
  hipLaunchKernelGGL(k_softmax, dim3(64), dim3(256), 0, stream, scores, wts);
  hipLaunchKernelGGL(k_ctx_comb, dim3(64), dim3(512), 0, stream, part, mz, ctx);
}

// Round 6
// 121.959 us; speedup vs baseline: 1.3657x; 1.0068x over previous
//
#include <hip/hip_runtime.h>

#define B_ 64
#define T_ 2048
#define H_ 512
#define A_ 512

typedef unsigned short u16;
typedef __attribute__((ext_vector_type(8))) short bf16x8;
typedef __attribute__((ext_vector_type(4))) float f32x4;

__device__ __forceinline__ u16 f2bf(float f) {
  unsigned u = __float_as_uint(f);
  unsigned r = (u + 0x7FFFu + ((u >> 16) & 1u)) >> 16;  // RNE
  return (u16)r;
}

__device__ __forceinline__ float bf2f(u16 h) {
  return __uint_as_float(((unsigned)h) << 16);
}

__device__ __forceinline__ float fast_tanh(float x) {
  float e = __expf(2.0f * x);
  return 1.0f - 2.0f * __builtin_amdgcn_rcpf(e + 1.0f);
}

// Barrier that waits ONLY LDS ops: in-flight global loads survive it (T4).
// (__syncthreads would emit s_waitcnt vmcnt(0) and drain the prefetch.)
#define BAR_LDS() asm volatile("s_waitcnt lgkmcnt(0)\n\ts_barrier" ::: "memory")

// ---------------- K1: merged W_enc conversion + dec_proj -------------------
// blocks [0,128): W_enc fp32 -> bf16 fragment-tiled
//   unit idx = ks*2048 + (a>>4)*64 + q*16 + (a&15), holds W_enc[a][ks*32+q*8..+8]
// blocks [128,640): dec_proj[b][a] = dot(dec[b,:], W_dec[a,:])
__global__ void k_prep(const float* __restrict__ W, u16* __restrict__ wsB,
                       const float* __restrict__ dec, const float* __restrict__ Wd,
                       float* __restrict__ dp) {
  __shared__ float dl[H_];
  int tid = threadIdx.x;
  int bx = blockIdx.x;
  if (bx < 128) {
    int u = bx * 256 + tid;  // 32768 units
    int a = u >> 6;
    int hq = u & 63;
    int ks = hq >> 2;
    int q = hq & 3;
    const float4* src = (const float4*)(W + a * H_ + hq * 8);
    float4 x0 = src[0], x1 = src[1];
    uint4 pk;
    pk.x = (unsigned)f2bf(x0.x) | ((unsigned)f2bf(x0.y) << 16);
    pk.y = (unsigned)f2bf(x0.z) | ((unsigned)f2bf(x0.w) << 16);
    pk.z = (unsigned)f2bf(x1.x) | ((unsigned)f2bf(x1.y) << 16);
    pk.w = (unsigned)f2bf(x1.z) | ((unsigned)f2bf(x1.w) << 16);
    int dst = ks * 2048 + (a >> 4) * 64 + q * 16 + (a & 15);
    ((uint4*)wsB)[dst] = pk;
  } else {
    int e = bx - 128;        // 512 blocks
    int b = e >> 3;
    int a0 = (e & 7) * 64;
    dl[tid] = dec[b * H_ + tid];
    dl[tid + 256] = dec[b * H_ + tid + 256];
    __syncthreads();
    int al = tid >> 2, p = tid & 3;
    const float4* wr = (const float4*)(Wd + (a0 + al) * H_ + p * 128);
    const float4* dv = (const float4*)(dl + p * 128);
    float s = 0.f;
#pragma unroll 8
    for (int i = 0; i < 32; ++i) {
      float4 w4 = wr[i], d4 = dv[i];
      s += w4.x * d4.x + w4.y * d4.y + w4.z * d4.z + w4.w * d4.w;
    }
    s += __shfl_xor(s, 1);
    s += __shfl_xor(s, 2);
    if (p == 0) dp[b * H_ + a0 + al] = s;
  }
}

// ---------------- K2: fused GEMM + tanh + V-dot + local softmax + PV -------
// BM=64, BN=512, 8 waves; wave w owns cols [w*64, w*64+64).
// A-tile staged in 4 chunks (4 K-steps each) with a 2-chunk-deep prefetch
// pipeline; chunk barriers wait LDS ONLY (BAR_LDS) so global loads stay in
// flight across them. Epilogue: scores + block-local softmax (all-wave
// redundant, no serial section) + partial context from the LDS A-tile.
// LDS unit u (16B, 8 bf16) = ks*256 + m*64 + q*16 + r
//   holds enc_bf16[row = m*16+r][cols ks*32+q*8 .. +8]
__launch_bounds__(512, 4)
__global__ void k_scores(const float* __restrict__ enc, const u16* __restrict__ wsB,
                         const float* __restrict__ dpj, const float* __restrict__ V,
                         float* __restrict__ scores, float* __restrict__ part,
                         float* __restrict__ mz) {
  __shared__ __attribute__((aligned(16))) u16 Ab[64 * 512];  // 64 KB
  __shared__ float red[8][64];
  int tid = threadIdx.x;
  int w = tid >> 6, l = tid & 63;
  int q = l >> 4, r = l & 15;
  int m0 = blockIdx.x * 64;
  int b = m0 >> 11;

  // staging decode: thread owns unit it*512+tid for it=0..7
  // row = sm*16+sr, cols = (tid>>8)*32 + sq*8 + it*64  (ks = it*2 + (tid>>8))
  int rem = tid & 255;
  int sm = rem >> 6, sq = (rem >> 4) & 3, sr = rem & 15;
  const float* ab = enc + (size_t)(m0 + sm * 16 + sr) * H_ + (tid >> 8) * 32 + sq * 8;

#define LOADC(y0, y1, y2, y3, c)                                      \
  {                                                                   \
    y0 = *((const float4*)(ab + (2 * (c)) * 64));                     \
    y1 = *((const float4*)(ab + (2 * (c)) * 64 + 4));                 \
    y2 = *((const float4*)(ab + (2 * (c) + 1) * 64));                 \
    y3 = *((const float4*)(ab + (2 * (c) + 1) * 64 + 4));             \
  }
#define STG_WRITE(y0, y1, it)                                         \
  {                                                                   \
    uint4 pk;                                                         \
    pk.x = (unsigned)f2bf(y0.x) | ((unsigned)f2bf(y0.y) << 16);       \
    pk.y = (unsigned)f2bf(y0.z) | ((unsigned)f2bf(y0.w) << 16);       \
    pk.z = (unsigned)f2bf(y1.x) | ((unsigned)f2bf(y1.y) << 16);       \
    pk.w = (unsigned)f2bf(y1.z) | ((unsigned)f2bf(y1.w) << 16);       \
    ((uint4*)Ab)[(it) * 512 + tid] = pk;                              \
  }
#define WRITEC(y0, y1, y2, y3, c)                                     \
  {                                                                   \
    STG_WRITE(y0, y1, 2 * (c))                                        \
    STG_WRITE(y2, y3, 2 * (c) + 1)                                    \
  }
#define COMPUTE4(c)                                                   \
  {                                                                   \
    _Pragma("unroll") for (int kk = 0; kk < 4; ++kk) {                \
      int ks = (c) * 4 + kk;                                          \
      bf16x8 bb[4], af[4];                                            \
      _Pragma("unroll") for (int n = 0; n < 4; ++n)                   \
          bb[n] = bfrag[ks * 2048 + (w * 4 + n) * 64 + l];            \
      _Pragma("unroll") for (int m = 0; m < 4; ++m)                   \
          af[m] = *((const bf16x8*)&Ab[(ks * 256 + m * 64 + l) * 8]); \
      __builtin_amdgcn_s_setprio(1);                                  \
      _Pragma("unroll") for (int m = 0; m < 4; ++m)                   \
          _Pragma("unroll") for (int n = 0; n < 4; ++n)               \
              acc[m][n] = __builtin_amdgcn_mfma_f32_16x16x32_bf16(    \
                  af[m], bb[n], acc[m][n], 0, 0, 0);                  \
      __builtin_amdgcn_s_setprio(0);                                  \
    }                                                                 \
  }

  f32x4 acc[4][4];
#pragma unroll
  for (int m = 0; m < 4; ++m)
#pragma unroll
    for (int n = 0; n < 4; ++n) acc[m][n] = (f32x4){0.f, 0.f, 0.f, 0.f};

  const bf16x8* bfrag = (const bf16x8*)wsB;

  // ---- 2-deep software pipeline over 4 chunks (16 K-steps) ----
  float4 ya0, ya1, ya2, ya3, yb0, yb1, yb2, yb3;
  LOADC(ya0, ya1, ya2, ya3, 0)
  LOADC(yb0, yb1, yb2, yb3, 1)
  WRITEC(ya0, ya1, ya2, ya3, 0)
  BAR_LDS();
  LOADC(ya0, ya1, ya2, ya3, 2)
  COMPUTE4(0)
  WRITEC(yb0, yb1, yb2, yb3, 1)
  BAR_LDS();
  LOADC(yb0, yb1, yb2, yb3, 3)
  COMPUTE4(1)
  WRITEC(ya0, ya1, ya2, ya3, 2)
  BAR_LDS();
  COMPUTE4(2)
  WRITEC(yb0, yb1, yb2, yb3, 3)
  BAR_LDS();
  COMPUTE4(3)

  // ---- scores epilogue: sp = sum_cols V[col]*tanh(acc + dec_proj) ----
  float sp[4][4] = {};
  const float* db = dpj + b * A_;
#pragma unroll
  for (int n = 0; n < 4; ++n) {
    int col = w * 64 + n * 16 + r;
    float vv = V[col];
    float dd = db[col];
#pragma unroll
    for (int m = 0; m < 4; ++m)
#pragma unroll
      for (int j = 0; j < 4; ++j)
        sp[m][j] = fmaf(vv, fast_tanh(acc[m][n][j] + dd), sp[m][j]);
  }
#pragma unroll
  for (int m = 0; m < 4; ++m)
#pragma unroll
    for (int j = 0; j < 4; ++j) {
      float v = sp[m][j];
      v += __shfl_xor(v, 1);
      v += __shfl_xor(v, 2);
      v += __shfl_xor(v, 4);
      v += __shfl_xor(v, 8);
      sp[m][j] = v;
    }
  float outv = 0.f;
#pragma unroll
  for (int mm = 0; mm < 4; ++mm)
#pragma unroll
    for (int jj = 0; jj < 4; ++jj)
      if (r == mm * 4 + jj) outv = sp[mm][jj];
  red[w][(r >> 2) * 16 + q * 4 + (r & 3)] = outv;
  BAR_LDS();

  // ---- ALL waves: final row scores + local softmax (no serial section) ----
  float s = 0.f;
#pragma unroll
  for (int ww = 0; ww < 8; ++ww) s += red[ww][l];
  if (w == 0) scores[m0 + l] = s;
  float mx = s;
#pragma unroll
  for (int off = 1; off <= 32; off <<= 1) mx = fmaxf(mx, __shfl_xor(mx, off));
  float e = __expf(s - mx);
  float Z = e;
#pragma unroll
  for (int off = 1; off <= 32; off <<= 1) Z += __shfl_xor(Z, off);
  if (tid == 0) {
    mz[blockIdx.x * 2] = mx;
    mz[blockIdx.x * 2 + 1] = Z;
  }
  float em[4];
#pragma unroll
  for (int m = 0; m < 4; ++m) em[m] = __shfl(e, m * 16 + r);

  // ---- PV: partial ctx[col] = sum_rows e_row * enc_bf16[row][col] ----
  // wave w covers ks = 2w, 2w+1 (cols w*64 .. w*64+64).
  {
    float pv0[8], pv1[8];
#pragma unroll
    for (int j = 0; j < 8; ++j) { pv0[j] = 0.f; pv1[j] = 0.f; }
#pragma unroll
    for (int ksl = 0; ksl < 2; ++ksl) {
      int ks = 2 * w + ksl;
#pragma unroll
      for (int m = 0; m < 4; ++m) {
        uint4 pk = ((const uint4*)Ab)[ks * 256 + m * 64 + l];
        float er = em[m];
        float v0 = bf2f((u16)(pk.x & 0xffff)), v1 = bf2f((u16)(pk.x >> 16));
        float v2 = bf2f((u16)(pk.y & 0xffff)), v3 = bf2f((u16)(pk.y >> 16));
        float v4 = bf2f((u16)(pk.z & 0xffff)), v5 = bf2f((u16)(pk.z >> 16));
        float v6 = bf2f((u16)(pk.w & 0xffff)), v7 = bf2f((u16)(pk.w >> 16));
        if (ksl == 0) {
          pv0[0] = fmaf(er, v0, pv0[0]); pv0[1] = fmaf(er, v1, pv0[1]);
          pv0[2] = fmaf(er, v2, pv0[2]); pv0[3] = fmaf(er, v3, pv0[3]);
          pv0[4] = fmaf(er, v4, pv0[4]); pv0[5] = fmaf(er, v5, pv0[5]);
          pv0[6] = fmaf(er, v6, pv0[6]); pv0[7] = fmaf(er, v7, pv0[7]);
        } else {
          pv1[0] = fmaf(er, v0, pv1[0]); pv1[1] = fmaf(er, v1, pv1[1]);
          pv1[2] = fmaf(er, v2, pv1[2]); pv1[3] = fmaf(er, v3, pv1[3]);
          pv1[4] = fmaf(er, v4, pv1[4]); pv1[5] = fmaf(er, v5, pv1[5]);
          pv1[6] = fmaf(er, v6, pv1[6]); pv1[7] = fmaf(er, v7, pv1[7]);
        }
      }
    }
#pragma unroll
    for (int j = 0; j < 8; ++j) {
      float a0 = pv0[j], a1 = pv1[j];
      a0 += __shfl_xor(a0, 1); a1 += __shfl_xor(a1, 1);
      a0 += __shfl_xor(a0, 2); a1 += __shfl_xor(a1, 2);
      a0 += __shfl_xor(a0, 4); a1 += __shfl_xor(a1, 4);
      a0 += __shfl_xor(a0, 8); a1 += __shfl_xor(a1, 8);
      pv0[j] = a0; pv1[j] = a1;
    }
    float ov = 0.f;
#pragma unroll
    for (int jj = 0; jj < 8; ++jj) {
      if (r == jj) ov = pv0[jj];
      if (r == jj + 8) ov = pv1[jj];
    }
    int col = w * 64 + (r >> 3) * 32 + q * 8 + (r & 7);
    part[(size_t)blockIdx.x * 512 + col] = ov;
  }
#undef LOADC
#undef STG_WRITE
#undef WRITEC
#undef COMPUTE4
}

// ---------------- K3: softmax over T per b -> weights (output) -------------
__global__ void k_softmax(const float* __restrict__ scores, float* __restrict__ wts) {
  __shared__ float rm[4], rs[4];
  int b = blockIdx.x, tid = threadIdx.x;
  float s[8];
#pragma unroll
  for (int i = 0; i < 8; ++i) s[i] = scores[b * T_ + i * 256 + tid];
  float mx = s[0];
#pragma unroll
  for (int i = 1; i < 8; ++i) mx = fmaxf(mx, s[i]);
#pragma unroll
  for (int off = 1; off <= 32; off <<= 1) mx = fmaxf(mx, __shfl_xor(mx, off));
  if ((tid & 63) == 0) rm[tid >> 6] = mx;
  __syncthreads();
  mx = fmaxf(fmaxf(rm[0], rm[1]), fmaxf(rm[2], rm[3]));
  float ex[8], se = 0.f;
#pragma unroll
  for (int i = 0; i < 8; ++i) { ex[i] = __expf(s[i] - mx); se += ex[i]; }
#pragma unroll
  for (int off = 1; off <= 32; off <<= 1) se += __shfl_xor(se, off);
  if ((tid & 63) == 0) rs[tid >> 6] = se;
  __syncthreads();
  se = rs[0] + rs[1] + rs[2] + rs[3];
  float inv = 1.0f / se;
#pragma unroll
  for (int i = 0; i < 8; ++i) wts[b * T_ + i * 256 + tid] = ex[i] * inv;
}

// ---------------- K4: flash recombine partial contexts -> context ----------
__global__ void k_ctx_comb(const float* __restrict__ part, const float* __restrict__ mz,
                           float* __restrict__ ctx) {
  __shared__ float sM[32], sZ[32];
  int b = blockIdx.x, tid = threadIdx.x;  // 512 threads, thread = h
  if (tid < 32) {
    sM[tid] = mz[(b * 32 + tid) * 2];
    sZ[tid] = mz[(b * 32 + tid) * 2 + 1];
  }
  __syncthreads();
  float M = sM[0];
#pragma unroll
  for (int i = 1; i < 32; ++i) M = fmaxf(M, sM[i]);
  float denom = 0.f;
#pragma unroll
  for (int i = 0; i < 32; ++i) denom += sZ[i] * __expf(sM[i] - M);
  float s = 0.f;
#pragma unroll
  for (int i = 0; i < 32; ++i)
    s += part[((size_t)b * 32 + i) * 512 + tid] * __expf(sM[i] - M);
  ctx[b * 512 + tid] = s / denom;
}

extern "C" void kernel_launch(void* const* d_in, const int* in_sizes, int n_in,
                              void* d_out, int out_size, void* d_ws, size_t ws_size,
                              hipStream_t stream) {
  const float* enc  = (const float*)d_in[0];
  const float* dec  = (const float*)d_in[1];
  const float* Wenc = (const float*)d_in[2];
  const float* Wdec = (const float*)d_in[3];
  const float* V    = (const float*)d_in[4];
  float* out = (float*)d_out;
  char* ws = (char*)d_ws;

  u16* wsB      = (u16*)ws;                            // 512 KB bf16 tiled W_enc
  float* dpj    = (float*)(ws + 512 * 1024);           // 128 KB dec_proj
  float* scores = (float*)(ws + 640 * 1024);           // 512 KB scores
  float* part   = (float*)(ws + 1152 * 1024);          // 4 MB ctx partials (2048 x 512)
  float* mz     = (float*)(ws + 1152 * 1024 + 4 * 1024 * 1024);  // 16 KB (m,Z)

  float* ctx = out;            // [B,H] = 32768 floats
  float* wts = out + B_ * H_;  // [B,T] = 131072 floats

  hipLaunchKernelGGL(k_prep, dim3(640), dim3(256), 0, stream, Wenc, wsB, dec, Wdec, dpj);
  hipLaunchKernelGGL(k_scores, dim3(2048), dim3(512), 0, stream, enc, wsB, dpj, V,
                     scores, part, mz);
  hipLaunchKernelGGL(k_softmax, dim3(64), dim3(256), 0, stream, scores, wts);
  hipLaunchKernelGGL(k_ctx_comb, dim3(64), dim3(512), 0, stream, part, mz, ctx);
}